// Round 1
// baseline (349.883 us; speedup 1.0000x reference)
//
#include <hip/hip_runtime.h>
#include <hip/hip_bf16.h>
#include <math.h>

// ---------------------------------------------------------------------------
// Expansion kernel: out[b,80,80] from per-sample generated tensor-product
// weights.  Q-form fusion: out[b,uv] = sum_{c,w} h[b,c]*x[b,w]*lw2[c,n(w,uv)]
// -> per-sample A-vector Q[b, w*64+c] (bf16, register-resident) x fixed
// B-matrix (transposed lw2, bf16) via mfma_f32_16x16x32_bf16.
// ---------------------------------------------------------------------------

typedef short bf16x8 __attribute__((ext_vector_type(8)));
typedef float f32x4 __attribute__((ext_vector_type(4)));

static __device__ __forceinline__ short f2bf(float f) {
  unsigned u = __builtin_bit_cast(unsigned, f);
  u = u + 0x7fffu + ((u >> 16) & 1u);   // round-to-nearest-even
  return (short)(u >> 16);
}

// ---- pre-pass 1: LW2 [64][36864] f32 -> LW2T bf16 [36864][64] ------------
__global__ void k_transpose(const float* __restrict__ lw2, short* __restrict__ lw2t) {
  __shared__ float tile[64][65];
  int n0 = blockIdx.x * 64;
  int t = threadIdx.x;
#pragma unroll
  for (int k = 0; k < 16; ++k) {
    int idx = k * 256 + t;
    int c = idx >> 6, j = idx & 63;
    tile[c][j] = lw2[(size_t)c * 36864 + n0 + j];
  }
  __syncthreads();
#pragma unroll
  for (int k = 0; k < 16; ++k) {
    int idx = k * 256 + t;
    int n = idx >> 6, c = idx & 63;
    lw2t[(size_t)(n0 + n) * 64 + c] = f2bf(tile[c][n]);
  }
}

// ---- pre-pass 2: packed bias matrices ------------------------------------
// BB00[uv<1024][96]: [0:64)=bw2[c,uv], [64:80)=lb2[w*1024+uv], [80]=bb2[uv], rest 0
// BB11[uv< 256][96]: same with offsets 1024 / 16384+w*256 / 1024+uv
// BB01[uv< 512][32]: [0:16)=lb2[20480+w*512+uv], rest 0
// BB10[uv< 512][32]: [0:16)=lb2[28672+w*512+uv], rest 0
__global__ void k_bias(const float* __restrict__ bw2, const float* __restrict__ lb2,
                       const float* __restrict__ bb2,
                       short* __restrict__ bb00, short* __restrict__ bb11,
                       short* __restrict__ bb01, short* __restrict__ bb10) {
  int r = blockIdx.x * 256 + threadIdx.x;
  if (r < 1024) {
    int uv = r;
    for (int k = 0; k < 64; ++k) bb00[uv * 96 + k] = f2bf(bw2[k * 1280 + uv]);
    for (int w = 0; w < 16; ++w) bb00[uv * 96 + 64 + w] = f2bf(lb2[w * 1024 + uv]);
    bb00[uv * 96 + 80] = f2bf(bb2[uv]);
    for (int k = 81; k < 96; ++k) bb00[uv * 96 + k] = 0;
  } else if (r < 1280) {
    int uv = r - 1024;
    for (int k = 0; k < 64; ++k) bb11[uv * 96 + k] = f2bf(bw2[k * 1280 + 1024 + uv]);
    for (int w = 0; w < 16; ++w) bb11[uv * 96 + 64 + w] = f2bf(lb2[16384 + w * 256 + uv]);
    bb11[uv * 96 + 80] = f2bf(bb2[1024 + uv]);
    for (int k = 81; k < 96; ++k) bb11[uv * 96 + k] = 0;
  } else if (r < 1792) {
    int uv = r - 1280;
    for (int w = 0; w < 16; ++w) bb01[uv * 32 + w] = f2bf(lb2[20480 + w * 512 + uv]);
    for (int k = 16; k < 32; ++k) bb01[uv * 32 + k] = 0;
  } else if (r < 2304) {
    int uv = r - 1792;
    for (int w = 0; w < 16; ++w) bb10[uv * 32 + w] = f2bf(lb2[28672 + w * 512 + uv]);
    for (int k = 16; k < 32; ++k) bb10[uv * 32 + k] = 0;
  }
}

// ---- pre-pass 3: per-sample h, h2, x0, x1 --------------------------------
__global__ void k_samples(const float* __restrict__ feat, const float* __restrict__ ne,
                          const float* __restrict__ W0, const float* __restrict__ W1,
                          const float* __restrict__ lw1, const float* __restrict__ lb1,
                          const float* __restrict__ bw1, const float* __restrict__ bb1,
                          float* __restrict__ H, float* __restrict__ H2,
                          float* __restrict__ X0, float* __restrict__ X1) {
  int b = blockIdx.x;
  int t = threadIdx.x;               // 192 threads
  __shared__ float sne[128];
  __shared__ float sf[320];
  if (t < 128) sne[t] = ne[(size_t)b * 128 + t];
  for (int i = t; i < 320; i += 192) sf[i] = feat[(size_t)b * 320 + i];
  __syncthreads();
  if (t < 64) {
    float a = lb1[t];
    for (int k = 0; k < 128; ++k) a += sne[k] * lw1[k * 64 + t];
    H[(size_t)b * 64 + t] = a / (1.0f + expf(-a));
  } else if (t < 128) {
    int c = t - 64;
    float a = bb1[c];
    for (int k = 0; k < 128; ++k) a += sne[k] * bw1[k * 64 + c];
    H2[(size_t)b * 64 + c] = a / (1.0f + expf(-a));
  } else if (t < 144) {
    int v = t - 128;
    float a = 0.0f;
    for (int u = 0; u < 128; ++u) a += sf[u] * W0[u * 16 + v];
    X0[(size_t)b * 16 + v] = a * 0.08838834764831845f;  // 1/sqrt(128)
  } else {
    int idx = t - 144, v = idx / 3, j = idx % 3;        // idx < 48
    float a = 0.0f;
    for (int u = 0; u < 64; ++u) a += sf[128 + u * 3 + j] * W1[u * 16 + v];
    X1[(size_t)b * 48 + v * 3 + j] = a * 0.125f;        // 1/sqrt(64)
  }
}

// ---- main kernel ----------------------------------------------------------
template <int NOFF, int NSTR, int NBIAS, int BBW>
static __device__ __forceinline__ void mm_pair(
    const short* __restrict__ LW2T, const short* __restrict__ BB,
    const bf16x8 (&A)[32], const bf16x8* __restrict__ Ab,
    int uv0, int uv1, int col, int q, f32x4& acc0, f32x4& acc1) {
#pragma unroll
  for (int kk = 0; kk < 32; ++kk) {
    int base = kk * 32 + q * 8;
    int w = base >> 6, c0 = base & 63;
    const bf16x8 B0 = *(const bf16x8*)(LW2T + (size_t)(NOFF + w * NSTR + uv0 + col) * 64 + c0);
    const bf16x8 B1 = *(const bf16x8*)(LW2T + (size_t)(NOFF + w * NSTR + uv1 + col) * 64 + c0);
    acc0 = __builtin_amdgcn_mfma_f32_16x16x32_bf16(A[kk], B0, acc0, 0, 0, 0);
    acc1 = __builtin_amdgcn_mfma_f32_16x16x32_bf16(A[kk], B1, acc1, 0, 0, 0);
  }
#pragma unroll
  for (int kk = 0; kk < NBIAS; ++kk) {
    int base = kk * 32 + q * 8;
    const bf16x8 B0 = *(const bf16x8*)(BB + (uv0 + col) * BBW + base);
    const bf16x8 B1 = *(const bf16x8*)(BB + (uv1 + col) * BBW + base);
    acc0 = __builtin_amdgcn_mfma_f32_16x16x32_bf16(Ab[kk], B0, acc0, 0, 0, 0);
    acc1 = __builtin_amdgcn_mfma_f32_16x16x32_bf16(Ab[kk], B1, acc1, 0, 0, 0);
  }
}

__global__ __launch_bounds__(256, 2) void k_main(
    const short* __restrict__ LW2T,
    const short* __restrict__ BB00, const short* __restrict__ BB11,
    const short* __restrict__ BB01, const short* __restrict__ BB10,
    const float* __restrict__ H, const float* __restrict__ H2,
    const float* __restrict__ X0, const float* __restrict__ X1,
    float* __restrict__ out) {
  constexpr float S00 = 0.0625f;                  // 1/16
  constexpr float S3 = 0.036084391824351614f;     // (1/sqrt(3))/16

  int wg = blockIdx.x;
  int btile = wg >> 1, g = wg & 1;
  int b0 = btile << 4;
  int t = threadIdx.x;
  int lane = t & 63, wave = t >> 6;
  int col = lane & 15, q = lane >> 4;

  __shared__ float sH[16][68];
  __shared__ float sH2[16][68];
  __shared__ float sX0[16][17];
  __shared__ float sX1[16][51];

  for (int i = t; i < 1024; i += 256) {
    int b = i >> 6, c = i & 63;
    sH[b][c]  = H[(size_t)(b0 + b) * 64 + c];
    sH2[b][c] = H2[(size_t)(b0 + b) * 64 + c];
  }
  sX0[t >> 4][t & 15] = X0[(size_t)(b0 + (t >> 4)) * 16 + (t & 15)];
  for (int i = t; i < 768; i += 256)
    sX1[i / 48][i % 48] = X1[(size_t)(b0 + i / 48) * 48 + (i % 48)];
  __syncthreads();

  bf16x8 A[32];
  bf16x8 Ab[3];

  // =============== Phase A: Q0 = h * x0  (paths 00, 11) ===================
#pragma unroll
  for (int kk = 0; kk < 32; ++kk) {
    int base = kk * 32 + q * 8;
    int w = base >> 6, c0 = base & 63;
    float xw = sX0[col][w];
    bf16x8 a;
#pragma unroll
    for (int e = 0; e < 8; ++e) a[e] = f2bf(sH[col][c0 + e] * xw);
    A[kk] = a;
  }
#pragma unroll
  for (int kk = 0; kk < 3; ++kk) {
    bf16x8 a;
#pragma unroll
    for (int e = 0; e < 8; ++e) {
      int k = kk * 32 + q * 8 + e;
      float v = 0.0f;
      if (k < 64) v = sH2[col][k];
      else if (k < 80) v = sX0[col][k - 64];
      else if (k == 80) v = 1.0f;
      a[e] = f2bf(v);
    }
    Ab[kk] = a;
  }

  // path00: uv = u*32+v < 1024, n = w*1024+uv, out (u, v), scale 1/16
#pragma unroll 1
  for (int pp = 0; pp < 4; ++pp) {
    int uv0 = (g * 32 + wave * 8 + pp * 2) * 16;
    int uv1 = uv0 + 16;
    f32x4 acc0 = {0.f, 0.f, 0.f, 0.f}, acc1 = {0.f, 0.f, 0.f, 0.f};
    mm_pair<0, 1024, 3, 96>(LW2T, BB00, A, Ab, uv0, uv1, col, q, acc0, acc1);
#pragma unroll
    for (int i = 0; i < 4; ++i) {
      size_t ob = (size_t)(b0 + q * 4 + i) * 6400;
      int uA = uv0 + col, uB = uv1 + col;
      out[ob + (uA >> 5) * 80 + (uA & 31)] = acc0[i] * S00;
      out[ob + (uB >> 5) * 80 + (uB & 31)] = acc1[i] * S00;
    }
  }

  // path11: uv = u*16+v < 256, n = 16384+w*256+uv, out 3x3 diag blocks
  {
    int uv0 = (g * 8 + wave * 2) * 16;
    int uv1 = uv0 + 16;
    f32x4 acc0 = {0.f, 0.f, 0.f, 0.f}, acc1 = {0.f, 0.f, 0.f, 0.f};
    mm_pair<16384, 256, 3, 96>(LW2T, BB11, A, Ab, uv0, uv1, col, q, acc0, acc1);
#pragma unroll
    for (int i = 0; i < 4; ++i) {
      size_t ob = (size_t)(b0 + q * 4 + i) * 6400;
#pragma unroll
      for (int s = 0; s < 2; ++s) {
        int uv = (s ? uv1 : uv0) + col;
        float val = (s ? acc1[i] : acc0[i]) * S3;
        int u = uv >> 4, v = uv & 15;
        float* p = out + ob + (size_t)(32 + 3 * u) * 80 + (32 + 3 * v);
        p[0] = val;   p[1] = 0.f;   p[2] = 0.f;
        p[80] = 0.f;  p[81] = val;  p[82] = 0.f;
        p[160] = 0.f; p[161] = 0.f; p[162] = val;
      }
    }
  }

  // =============== Phase B: Q1j = h * x1[:, :, j]  (paths 01, 10) =========
#pragma unroll 1
  for (int j = 0; j < 3; ++j) {
#pragma unroll
    for (int kk = 0; kk < 32; ++kk) {
      int base = kk * 32 + q * 8;
      int w = base >> 6, c0 = base & 63;
      float xw = sX1[col][w * 3 + j];
      bf16x8 a;
#pragma unroll
      for (int e = 0; e < 8; ++e) a[e] = f2bf(sH[col][c0 + e] * xw);
      A[kk] = a;
    }
    bf16x8 A1;
#pragma unroll
    for (int e = 0; e < 8; ++e) {
      int k = q * 8 + e;
      A1[e] = (k < 16) ? f2bf(sX1[col][k * 3 + j]) : (short)0;
    }

    // path01: uv = u*16+v < 512, n = 20480+w*512+uv, out (u, 32+3v+j)
#pragma unroll 1
    for (int pp = 0; pp < 2; ++pp) {
      int uv0 = (g * 16 + wave * 4 + pp * 2) * 16;
      int uv1 = uv0 + 16;
      f32x4 acc0 = {0.f, 0.f, 0.f, 0.f}, acc1 = {0.f, 0.f, 0.f, 0.f};
      mm_pair<20480, 512, 1, 32>(LW2T, BB01, A, &A1, uv0, uv1, col, q, acc0, acc1);
#pragma unroll
      for (int i = 0; i < 4; ++i) {
        size_t ob = (size_t)(b0 + q * 4 + i) * 6400;
        int uA = uv0 + col, uB = uv1 + col;
        out[ob + (uA >> 4) * 80 + 32 + 3 * (uA & 15) + j] = acc0[i] * S3;
        out[ob + (uB >> 4) * 80 + 32 + 3 * (uB & 15) + j] = acc1[i] * S3;
      }
    }
    // path10: uv = u*32+v < 512, n = 28672+w*512+uv, out (32+3u+j, v)
#pragma unroll 1
    for (int pp = 0; pp < 2; ++pp) {
      int uv0 = (g * 16 + wave * 4 + pp * 2) * 16;
      int uv1 = uv0 + 16;
      f32x4 acc0 = {0.f, 0.f, 0.f, 0.f}, acc1 = {0.f, 0.f, 0.f, 0.f};
      mm_pair<28672, 512, 1, 32>(LW2T, BB10, A, &A1, uv0, uv1, col, q, acc0, acc1);
#pragma unroll
      for (int i = 0; i < 4; ++i) {
        size_t ob = (size_t)(b0 + q * 4 + i) * 6400;
        int uA = uv0 + col, uB = uv1 + col;
        out[ob + (size_t)(32 + 3 * (uA >> 5) + j) * 80 + (uA & 31)] = acc0[i] * S3;
        out[ob + (size_t)(32 + 3 * (uB >> 5) + j) * 80 + (uB & 31)] = acc1[i] * S3;
      }
    }
  }
}

// ---------------------------------------------------------------------------
extern "C" void kernel_launch(void* const* d_in, const int* in_sizes, int n_in,
                              void* d_out, int out_size, void* d_ws, size_t ws_size,
                              hipStream_t stream) {
  const float* feat = (const float*)d_in[0];
  const float* ne   = (const float*)d_in[1];
  const float* W0   = (const float*)d_in[2];
  const float* W1   = (const float*)d_in[3];
  const float* lw1  = (const float*)d_in[4];
  const float* lb1  = (const float*)d_in[5];
  const float* lw2  = (const float*)d_in[6];
  const float* lb2  = (const float*)d_in[7];
  const float* bw1  = (const float*)d_in[8];
  const float* bb1  = (const float*)d_in[9];
  const float* bw2  = (const float*)d_in[10];
  const float* bb2  = (const float*)d_in[11];

  char* ws = (char*)d_ws;
  short* LW2T = (short*)ws; ws += (size_t)36864 * 64 * 2;   // 4.72 MB
  short* BB00 = (short*)ws; ws += (size_t)1024 * 96 * 2;
  short* BB11 = (short*)ws; ws += (size_t)256 * 96 * 2;
  short* BB01 = (short*)ws; ws += (size_t)512 * 32 * 2;
  short* BB10 = (short*)ws; ws += (size_t)512 * 32 * 2;
  float* H  = (float*)ws;   ws += (size_t)4096 * 64 * 4;
  float* H2 = (float*)ws;   ws += (size_t)4096 * 64 * 4;
  float* X0 = (float*)ws;   ws += (size_t)4096 * 16 * 4;
  float* X1 = (float*)ws;   ws += (size_t)4096 * 48 * 4;
  (void)ws_size; (void)in_sizes; (void)n_in; (void)out_size;

  hipLaunchKernelGGL(k_transpose, dim3(576), dim3(256), 0, stream, lw2, LW2T);
  hipLaunchKernelGGL(k_bias, dim3(9), dim3(256), 0, stream, bw2, lb2, bb2,
                     BB00, BB11, BB01, BB10);
  hipLaunchKernelGGL(k_samples, dim3(4096), dim3(192), 0, stream,
                     feat, ne, W0, W1, lw1, lb1, bw1, bb1, H, H2, X0, X1);
  hipLaunchKernelGGL(k_main, dim3(512), dim3(256), 0, stream,
                     LW2T, BB00, BB11, BB01, BB10, H, H2, X0, X1, (float*)d_out);
}